// Round 13
// baseline (724.792 us; speedup 1.0000x reference)
//
#include <hip/hip_runtime.h>

#define HID 128
#define NGRAPH 512
#define NLAYERS 3
#define BN_EPS 1e-5f
#define NPB 256          // nodes per bucket (CSR build)
#define EB 4096          // edges per build block

typedef __attribute__((ext_vector_type(8))) short bf16x8;
typedef __attribute__((ext_vector_type(4))) float f32x4;

__device__ inline unsigned short f2bf(float x) {
    union { float f; unsigned u; } v; v.f = x;
    unsigned r = v.u + 0x7FFFu + ((v.u >> 16) & 1u);
    return (unsigned short)(r >> 16);
}
__device__ inline float bf2f(unsigned short b) {
    union { float f; unsigned u; } v; v.u = ((unsigned)b) << 16; return v.f;
}

// ---------------------------------------------------------------------------
// prep (one launch): zero stats+gsum | W split+transpose | x -> bf16
// ---------------------------------------------------------------------------
__global__ void k_prep(float* __restrict__ stats, float* __restrict__ gsum,
                       const float4* __restrict__ x4, ushort* __restrict__ xb, int total4,
                       const float* __restrict__ W1, ushort* __restrict__ w1h, ushort* __restrict__ w1l,
                       const float* __restrict__ W2, ushort* __restrict__ w2h, ushort* __restrict__ w2l,
                       int wtotal) {
    int b = blockIdx.x, t = threadIdx.x;
    if (b < 768) {
        if (b == 0) for (int l = 0; l < NLAYERS; ++l) stats[l * 256 + t] = 0.0f;
        gsum[b * 256 + t] = 0.0f;
    } else if (b < 1152) {
        int gid = (b - 768) * 256 + t;
        const float* W; ushort *Wh, *Wl; int e;
        if (gid < wtotal) { W = W1; Wh = w1h; Wl = w1l; e = gid; }
        else              { W = W2; Wh = w2h; Wl = w2l; e = gid - wtotal; }
        if (e < wtotal) {
            int l = e >> 14, rem = e & 16383, k = rem >> 7, n = rem & 127;
            float v = W[e];
            ushort hi = f2bf(v);
            ushort lo = f2bf(v - bf2f(hi));
            int o = (l << 14) + (n << 7) + k;
            Wh[o] = hi; Wl[o] = lo;
        }
    } else {
        int i = (b - 1152) * 256 + t;
        if (i < total4) {
            float4 v = x4[i];
            uint2 p;
            p.x = ((unsigned)f2bf(v.y) << 16) | f2bf(v.x);
            p.y = ((unsigned)f2bf(v.w) << 16) | f2bf(v.z);
            ((uint2*)xb)[i] = p;
        }
    }
}

// ---------------------------------------------------------------------------
// CSR build, deterministic two-level (NO global atomics)
// ---------------------------------------------------------------------------
__global__ __launch_bounds__(256) void k_ecount(const int* __restrict__ dst, int E,
                                                int* __restrict__ blkcnt) {
    __shared__ int hist[512];
    int t = threadIdx.x;
    hist[t] = 0; hist[t + 256] = 0;
    __syncthreads();
    int base = blockIdx.x * EB;
    #pragma unroll
    for (int i = 0; i < 16; ++i) {
        int e = base + i * 256 + t;
        if (e < E) atomicAdd(&hist[dst[e] >> 8], 1);
    }
    __syncthreads();
    blkcnt[blockIdx.x * 512 + t]       = hist[t];
    blkcnt[blockIdx.x * 512 + t + 256] = hist[t + 256];
}

__global__ __launch_bounds__(256) void k_btotal(const int* __restrict__ blkcnt, int eblk,
                                                int nb, int E, int* __restrict__ bbase,
                                                int* __restrict__ rowptrN) {
    __shared__ int tot[512];
    int t = threadIdx.x;
    for (int b = t; b < 512; b += 256) {
        int s = 0;
        for (int j = 0; j < eblk; ++j) s += blkcnt[j * 512 + b];
        tot[b] = s;
    }
    __syncthreads();
    if (t == 0) {
        int run = 0;
        for (int b = 0; b < nb; ++b) { int c = tot[b]; tot[b] = run; run += c; }
        *rowptrN = E;
    }
    __syncthreads();
    for (int b = t; b < nb; b += 256) bbase[b] = tot[b];
    if (t == 0) bbase[nb] = E;
}

__global__ __launch_bounds__(256) void k_colscan(int* __restrict__ blkcnt, int eblk,
                                                 const int* __restrict__ bbase) {
    __shared__ int sh[512];
    int t = threadIdx.x;
    int b = blockIdx.x;
    for (int j = t; j < eblk; j += 256) sh[j] = blkcnt[j * 512 + b];
    __syncthreads();
    if (t == 0) {
        int run = bbase[b];
        for (int j = 0; j < eblk; ++j) { int c = sh[j]; sh[j] = run; run += c; }
    }
    __syncthreads();
    for (int j = t; j < eblk; j += 256) blkcnt[j * 512 + b] = sh[j];
}

__global__ __launch_bounds__(256) void k_bscatter(const int* __restrict__ src,
                                                  const int* __restrict__ dst, int E,
                                                  const int* __restrict__ blkcnt,
                                                  unsigned* __restrict__ pairs) {
    __shared__ int hist[512];    // local cursor (starts at 0)
    __shared__ int lbase[512];   // absolute base for this block's chunk per bucket
    int t = threadIdx.x;
    hist[t] = 0; hist[t + 256] = 0;
    lbase[t]       = blkcnt[blockIdx.x * 512 + t];
    lbase[t + 256] = blkcnt[blockIdx.x * 512 + t + 256];
    __syncthreads();
    int base = blockIdx.x * EB;
    #pragma unroll
    for (int i = 0; i < 16; ++i) {
        int e = base + i * 256 + t;
        if (e < E) {
            int d = dst[e];
            int b = d >> 8;
            int pos = lbase[b] + atomicAdd(&hist[b], 1);
            pairs[pos] = ((unsigned)(d & 255) << 24) | (unsigned)src[e];
        }
    }
}

__global__ __launch_bounds__(256) void k_bbuild(const unsigned* __restrict__ pairs,
                                                const int* __restrict__ bbase, int N,
                                                int* __restrict__ rowptr, int* __restrict__ csr) {
    __shared__ int cnt[256];
    __shared__ int off[256];
    int t = threadIdx.x;
    int b = blockIdx.x;
    int base = bbase[b], bcount = bbase[b + 1] - base;
    cnt[t] = 0;
    __syncthreads();
    for (int i = t; i < bcount; i += 256) atomicAdd(&cnt[pairs[base + i] >> 24], 1);
    __syncthreads();
    off[t] = cnt[t];
    __syncthreads();
    for (int s = 1; s < 256; s <<= 1) {
        int v = (t >= s) ? off[t - s] : 0;
        __syncthreads();
        off[t] += v;
        __syncthreads();
    }
    int excl = (t == 0) ? 0 : off[t - 1];
    int node = b * NPB + t;
    if (node < N) rowptr[node] = base + excl;
    cnt[t] = excl;                      // becomes per-node cursor
    __syncthreads();
    for (int i = t; i < bcount; i += 256) {
        unsigned p = pairs[base + i];
        int dl = p >> 24;
        int pos = base + atomicAdd(&cnt[dl], 1);
        csr[pos] = (int)(p & 0xFFFFFFu);
    }
}

// ---------------------------------------------------------------------------
// FUSED per-layer kernel: CSR gather (bf16 h) + inline BN fold of prev layer
// + MFMA MLP (A bf16, W bf16 hi+lo -> 2 MFMAs/tile) + BN stats + pool sums.
// LDS 16 KB (z0 bf16, z1 overlays), 8 blocks/CU.
// ---------------------------------------------------------------------------
__global__ __launch_bounds__(256, 8) void k_gin_layer(
        const int* __restrict__ rowptr, const int* __restrict__ csr_src,
        const uint2* __restrict__ hinb,
        const float* __restrict__ prev_stats,      // null for layer 0; else sum|sq (256)
        const float* __restrict__ g_row, const float* __restrict__ be_row,
        const float* __restrict__ eps_gin, int layer, const int* __restrict__ batch,
        const ushort* __restrict__ w1h, const ushort* __restrict__ w1l,
        const float* __restrict__ b1,
        const ushort* __restrict__ w2h, const ushort* __restrict__ w2l,
        const float* __restrict__ b2,
        ushort* __restrict__ Hout, float* __restrict__ stat_sum, float* __restrict__ stat_sq,
        float* __restrict__ gsum, int N) {
    __shared__ __align__(16) ushort smem[8192];    // 16 KB
    // phase A: z0 bf16 u4[0..1023] (64r x 16c swizzled)
    // phase Z (overlay): z1 bf16 us[0..8191]

    const int t = threadIdx.x;
    const int lane = t & 63;
    const int wv = t >> 6;
    const int li = lane & 15;
    const int kq = lane >> 4;
    const int n0 = wv * 32;
    const int row0 = blockIdx.x * 64;
    const int swz = (li & 7) * 4;

    // ---- gather phase: wave wv stages rows [wv*16, wv*16+16), 2 per iter ----
    {
        int half = lane >> 5;          // 0/1: which row of the pair
        int f = lane & 31;             // uint2 lane (4 bf16 features) within row
        float scv[4], shv[4];
        if (prev_stats) {
            float invn = 1.0f / (float)N;
            #pragma unroll
            for (int j = 0; j < 4; ++j) {
                int fi = f * 4 + j;
                float mu = prev_stats[fi] * invn;
                float var = prev_stats[128 + fi] * invn - mu * mu;
                float inv = rsqrtf(var + BN_EPS);
                float scj = g_row[fi] * inv;
                scv[j] = scj; shv[j] = be_row[fi] - mu * scj;
            }
        } else {
            #pragma unroll
            for (int j = 0; j < 4; ++j) { scv[j] = 1.0f; shv[j] = 0.0f; }
        }
        float e1 = 1.0f + eps_gin[layer];
        #pragma unroll
        for (int it = 0; it < 8; ++it) {
            int r = wv * 16 + it * 2 + half;      // local row
            int node = row0 + r;
            float ax = 0.f, ay = 0.f, az = 0.f, aw = 0.f;
            float cdeg = 0.f;
            if (node < N) {
                int beg = rowptr[node], end = rowptr[node + 1];
                uint2 hv = hinb[(size_t)node * 32 + f];
                ax = e1 * bf2f((ushort)hv.x); ay = e1 * bf2f((ushort)(hv.x >> 16));
                az = e1 * bf2f((ushort)hv.y); aw = e1 * bf2f((ushort)(hv.y >> 16));
                int p = beg;
                for (; p + 7 < end; p += 8) {
                    int s0 = csr_src[p],     s1 = csr_src[p + 1], s2 = csr_src[p + 2], s3 = csr_src[p + 3];
                    int s4 = csr_src[p + 4], s5 = csr_src[p + 5], s6 = csr_src[p + 6], s7 = csr_src[p + 7];
                    uint2 v0 = hinb[(size_t)s0 * 32 + f];
                    uint2 v1 = hinb[(size_t)s1 * 32 + f];
                    uint2 v2 = hinb[(size_t)s2 * 32 + f];
                    uint2 v3 = hinb[(size_t)s3 * 32 + f];
                    uint2 v4 = hinb[(size_t)s4 * 32 + f];
                    uint2 v5 = hinb[(size_t)s5 * 32 + f];
                    uint2 v6 = hinb[(size_t)s6 * 32 + f];
                    uint2 v7 = hinb[(size_t)s7 * 32 + f];
                    ax += ((bf2f((ushort)v0.x) + bf2f((ushort)v1.x)) + (bf2f((ushort)v2.x) + bf2f((ushort)v3.x)))
                        + ((bf2f((ushort)v4.x) + bf2f((ushort)v5.x)) + (bf2f((ushort)v6.x) + bf2f((ushort)v7.x)));
                    ay += ((bf2f((ushort)(v0.x >> 16)) + bf2f((ushort)(v1.x >> 16))) + (bf2f((ushort)(v2.x >> 16)) + bf2f((ushort)(v3.x >> 16))))
                        + ((bf2f((ushort)(v4.x >> 16)) + bf2f((ushort)(v5.x >> 16))) + (bf2f((ushort)(v6.x >> 16)) + bf2f((ushort)(v7.x >> 16))));
                    az += ((bf2f((ushort)v0.y) + bf2f((ushort)v1.y)) + (bf2f((ushort)v2.y) + bf2f((ushort)v3.y)))
                        + ((bf2f((ushort)v4.y) + bf2f((ushort)v5.y)) + (bf2f((ushort)v6.y) + bf2f((ushort)v7.y)));
                    aw += ((bf2f((ushort)(v0.y >> 16)) + bf2f((ushort)(v1.y >> 16))) + (bf2f((ushort)(v2.y >> 16)) + bf2f((ushort)(v3.y >> 16))))
                        + ((bf2f((ushort)(v4.y >> 16)) + bf2f((ushort)(v5.y >> 16))) + (bf2f((ushort)(v6.y >> 16)) + bf2f((ushort)(v7.y >> 16))));
                }
                for (; p < end; ++p) {
                    int s0 = csr_src[p];
                    uint2 v0 = hinb[(size_t)s0 * 32 + f];
                    ax += bf2f((ushort)v0.x); ay += bf2f((ushort)(v0.x >> 16));
                    az += bf2f((ushort)v0.y); aw += bf2f((ushort)(v0.y >> 16));
                }
                cdeg = e1 + (float)(end - beg);
            }
            float r0 = scv[0] * ax + cdeg * shv[0];
            float r1 = scv[1] * ay + cdeg * shv[1];
            float r2 = scv[2] * az + cdeg * shv[2];
            float r3 = scv[3] * aw + cdeg * shv[3];
            uint2 ph;
            ph.x = ((unsigned)f2bf(r1) << 16) | f2bf(r0);
            ph.y = ((unsigned)f2bf(r3) << 16) | f2bf(r2);
            int j = f >> 1;
            int d = r * 16 + (j ^ (r & 7));
            ((uint2*)smem)[d * 2 + (f & 1)] = ph;
        }
    }
    __syncthreads();

    f32x4 acc[4][2];
    #pragma unroll
    for (int i = 0; i < 4; ++i) {
        acc[i][0] = (f32x4){0.f, 0.f, 0.f, 0.f};
        acc[i][1] = (f32x4){0.f, 0.f, 0.f, 0.f};
    }

    // ---------------- GEMM1: z1 = z0 @ W1 (A bf16, W hi+lo from global) ----------------
    #pragma unroll
    for (int ch = 0; ch < 2; ++ch) {
        #pragma unroll
        for (int ks = 0; ks < 2; ++ks) {
            int kcol = ch * 8 + ks * 4 + kq;            // u4 col 0..15
            bf16x8 bh[2], bl[2];
            #pragma unroll
            for (int nt = 0; nt < 2; ++nt) {
                size_t wo = (size_t)(n0 + nt * 16 + li) * 128 + (ch * 64 + ks * 32 + kq * 8);
                bh[nt] = *(const bf16x8*)&w1h[wo];
                bl[nt] = *(const bf16x8*)&w1l[wo];
            }
            #pragma unroll
            for (int mt = 0; mt < 4; ++mt) {
                int r = mt * 16 + li;
                int hw = (r * 16 + (kcol ^ (li & 7))) * 8;
                bf16x8 ah = *(const bf16x8*)&smem[hw];
                #pragma unroll
                for (int nt = 0; nt < 2; ++nt) {
                    acc[mt][nt] = __builtin_amdgcn_mfma_f32_16x16x32_bf16(ah, bh[nt], acc[mt][nt], 0, 0, 0);
                    acc[mt][nt] = __builtin_amdgcn_mfma_f32_16x16x32_bf16(ah, bl[nt], acc[mt][nt], 0, 0, 0);
                }
            }
        }
    }

    // ---- z1 = relu(acc + b1) -> Z overlay (A-layout, bf16, swizzled) ----
    float bz0 = b1[n0 + li], bz1 = b1[n0 + 16 + li];
    __syncthreads();                    // all GEMM1 A-reads done before overwrite
    #pragma unroll
    for (int mt = 0; mt < 4; ++mt) {
        #pragma unroll
        for (int nt = 0; nt < 2; ++nt) {
            int c = n0 + nt * 16 + li;
            int dk = c >> 1;
            int halfbase = (dk >> 5) * 32;
            int dlow = dk & 31;
            int codd = c & 1;
            float bias = nt ? bz1 : bz0;
            #pragma unroll
            for (int reg = 0; reg < 4; ++reg) {
                int r = mt * 16 + kq * 4 + reg;
                float v = fmaxf(acc[mt][nt][reg] + bias, 0.f);
                int us = (r * 64 + halfbase + (dlow ^ ((r & 7) * 4))) * 2 + codd;
                smem[us] = f2bf(v);
            }
        }
    }
    #pragma unroll
    for (int i = 0; i < 4; ++i) {
        acc[i][0] = (f32x4){0.f, 0.f, 0.f, 0.f};
        acc[i][1] = (f32x4){0.f, 0.f, 0.f, 0.f};
    }
    __syncthreads();

    // ---------------- GEMM2: z2 = z1 @ W2 (A bf16, W hi+lo) ----------------
    #pragma unroll
    for (int ch = 0; ch < 2; ++ch) {
        #pragma unroll
        for (int ks = 0; ks < 2; ++ks) {
            bf16x8 bh[2], bl[2];
            #pragma unroll
            for (int nt = 0; nt < 2; ++nt) {
                size_t wo = (size_t)(n0 + nt * 16 + li) * 128 + (ch * 64 + ks * 32 + kq * 8);
                bh[nt] = *(const bf16x8*)&w2h[wo];
                bl[nt] = *(const bf16x8*)&w2l[wo];
            }
            int aoff = (ks * 16 + kq * 4) ^ swz;        // dwords
            #pragma unroll
            for (int mt = 0; mt < 4; ++mt) {
                int idx = ((mt * 16 + li) * 64 + ch * 32 + aoff) * 2;
                bf16x8 ah = *(const bf16x8*)&smem[idx];
                #pragma unroll
                for (int nt = 0; nt < 2; ++nt) {
                    acc[mt][nt] = __builtin_amdgcn_mfma_f32_16x16x32_bf16(ah, bh[nt], acc[mt][nt], 0, 0, 0);
                    acc[mt][nt] = __builtin_amdgcn_mfma_f32_16x16x32_bf16(ah, bl[nt], acc[mt][nt], 0, 0, 0);
                }
            }
        }
    }

    // ---- epilogue: bias+relu, store h (bf16), BN stats, per-graph pool sums ----
    float bb0 = b2[n0 + li], bb1 = b2[n0 + 16 + li];
    int btr[4][4];
    #pragma unroll
    for (int mt = 0; mt < 4; ++mt)
        #pragma unroll
        for (int reg = 0; reg < 4; ++reg) {
            int grow = row0 + mt * 16 + kq * 4 + reg;
            btr[mt][reg] = (grow < N) ? batch[grow] : -1;
        }
    float s0 = 0.f, q0 = 0.f, s1 = 0.f, q1 = 0.f;
    #pragma unroll
    for (int mt = 0; mt < 4; ++mt) {
        #pragma unroll
        for (int reg = 0; reg < 4; ++reg) {
            int grow = row0 + mt * 16 + kq * 4 + reg;
            if (grow < N) {
                float v0 = fmaxf(acc[mt][0][reg] + bb0, 0.f);
                float v1 = fmaxf(acc[mt][1][reg] + bb1, 0.f);
                Hout[(size_t)grow * HID + n0 + li]      = f2bf(v0);
                Hout[(size_t)grow * HID + n0 + 16 + li] = f2bf(v1);
                s0 += v0; q0 += v0 * v0; s1 += v1; q1 += v1 * v1;
            }
        }
    }
    s0 += __shfl_xor(s0, 16); s0 += __shfl_xor(s0, 32);
    q0 += __shfl_xor(q0, 16); q0 += __shfl_xor(q0, 32);
    s1 += __shfl_xor(s1, 16); s1 += __shfl_xor(s1, 32);
    q1 += __shfl_xor(q1, 16); q1 += __shfl_xor(q1, 32);
    if (kq == 0) {
        unsafeAtomicAdd(&stat_sum[n0 + li], s0);
        unsafeAtomicAdd(&stat_sq[n0 + li], q0);
        unsafeAtomicAdd(&stat_sum[n0 + 16 + li], s1);
        unsafeAtomicAdd(&stat_sq[n0 + 16 + li], q1);
    }
    // per-graph raw sums (affine applied later in k_mlp)
    int lastr = N - 1; if (lastr > row0 + 63) lastr = row0 + 63;
    int g_lo = batch[row0], g_hi = batch[lastr];
    int loff = layer * HID;
    for (int g = g_lo; g <= g_hi; ++g) {
        float p0 = 0.f, p1 = 0.f;
        #pragma unroll
        for (int mt = 0; mt < 4; ++mt)
            #pragma unroll
            for (int reg = 0; reg < 4; ++reg) {
                if (btr[mt][reg] == g) {
                    p0 += fmaxf(acc[mt][0][reg] + bb0, 0.f);
                    p1 += fmaxf(acc[mt][1][reg] + bb1, 0.f);
                }
            }
        p0 += __shfl_xor(p0, 16); p0 += __shfl_xor(p0, 32);
        p1 += __shfl_xor(p1, 16); p1 += __shfl_xor(p1, 32);
        if (kq == 0) {
            unsafeAtomicAdd(&gsum[(size_t)g * 384 + loff + n0 + li], p0);
            unsafeAtomicAdd(&gsum[(size_t)g * 384 + loff + n0 + 16 + li], p1);
        }
    }
}

// ---------------------------------------------------------------------------
// final MLP: fold BN affines from raw stats, apply to per-graph sums, 2-layer head
// ---------------------------------------------------------------------------
__global__ __launch_bounds__(128) void k_mlp(const int* __restrict__ batch, int N,
                     const float* __restrict__ gsum, const float* __restrict__ stats,
                     const float* __restrict__ gamma, const float* __restrict__ beta,
                     const float* __restrict__ w1, const float* __restrict__ b1,
                     const float* __restrict__ w2, const float* __restrict__ b2,
                     float* __restrict__ out) {
    __shared__ float gl[384];
    __shared__ float hh[128];
    int g = blockIdx.x, t = threadIdx.x;   // 128 threads
    int start, end;
    { int lo = 0, hi = N; while (lo < hi) { int m = (lo + hi) >> 1; if (batch[m] < g) lo = m + 1; else hi = m; } start = lo; }
    { int lo = start, hi = N; while (lo < hi) { int m = (lo + hi) >> 1; if (batch[m] < g + 1) lo = m + 1; else hi = m; } end = lo; }
    float cnt = (float)(end - start);
    float invc = 1.0f / fmaxf(cnt, 1.0f);
    float invn = 1.0f / (float)N;
    #pragma unroll
    for (int l = 0; l < NLAYERS; ++l) {
        float mu = stats[l * 256 + t] * invn;
        float var = stats[l * 256 + 128 + t] * invn - mu * mu;
        float inv = rsqrtf(var + BN_EPS);
        float sc = gamma[l * HID + t] * inv;
        float sh = beta[l * HID + t] - mu * sc;
        gl[l * 128 + t] = (gsum[(size_t)g * 384 + l * 128 + t] * sc + sh * cnt) * invc;
    }
    __syncthreads();
    float acc = b1[t];
    for (int k = 0; k < 384; ++k) acc = fmaf(gl[k], w1[k * HID + t], acc);
    hh[t] = fmaxf(acc, 0.f);
    __syncthreads();
    if (t < 10) {
        float a2 = b2[t];
        for (int k = 0; k < 128; ++k) a2 = fmaf(hh[k], w2[k * 10 + t], a2);
        out[g * 10 + t] = a2;
    }
}

// ---------------------------------------------------------------------------
extern "C" void kernel_launch(void* const* d_in, const int* in_sizes, int n_in,
                              void* d_out, int out_size, void* d_ws, size_t ws_size,
                              hipStream_t stream) {
    const float* x     = (const float*)d_in[0];
    const int*   ei    = (const int*)d_in[1];
    const int*   batch = (const int*)d_in[2];
    const float* W1    = (const float*)d_in[3];
    const float* b1    = (const float*)d_in[4];
    const float* W2    = (const float*)d_in[5];
    const float* b2    = (const float*)d_in[6];
    const float* gamma = (const float*)d_in[7];
    const float* beta  = (const float*)d_in[8];
    const float* epsg  = (const float*)d_in[9];
    const float* l1w   = (const float*)d_in[10];
    const float* l1b   = (const float*)d_in[11];
    const float* l2w   = (const float*)d_in[12];
    const float* l2b   = (const float*)d_in[13];

    const int N = in_sizes[0] / HID;
    const int E = in_sizes[1] / 2;
    const int* src = ei;
    const int* dst = ei + E;
    const int nb = (N + NPB - 1) / NPB;           // <= 512
    const int eblk = (E + EB - 1) / EB;           // <= 512

    float* w = (float*)d_ws;
    const size_t NF = (size_t)N * HID;
    float* zbuf   = w;                                       // pairs/blkcnt scratch (CSR build only)
    ushort* xb    = (ushort*)(w + NF);                       // x as bf16 (NF ushorts)
    ushort* hb[3] = { xb + NF, xb + 2 * NF, xb + 3 * NF };   // layer outputs, bf16
    float* stats  = w + 4 * NF;       // 3 * 256 (sum|sq per layer)
    float* gsum   = stats + 768;      // 512 * 384 (per-graph raw sums)
    int*   rowptr = (int*)(gsum + (size_t)NGRAPH * 384);     // N + 1
    int*   csr    = rowptr + N + 1;                          // E
    int*   bbase  = csr + E;                                 // nb + 1
    ushort* wt  = (ushort*)(((uintptr_t)(bbase + nb + 1) + 15) & ~(uintptr_t)15);
    ushort* w1h = wt;
    ushort* w1l = wt + 49152;
    ushort* w2h = wt + 98304;
    ushort* w2l = wt + 147456;

    unsigned* pairs  = (unsigned*)zbuf;             // E uints
    int*      blkcnt = (int*)(w + 2 * 1024 * 1024); // eblk*512 (inside zbuf region)

    const int total4 = (int)(NF / 4);
    const int prep_blocks = 1152 + (total4 + 255) / 256;
    k_prep<<<prep_blocks, 256, 0, stream>>>(stats, gsum, (const float4*)x, xb, total4,
                                            W1, w1h, w1l, W2, w2h, w2l, NLAYERS * HID * HID);

    // ---- build CSR (deterministic, no global atomics) ----
    k_ecount<<<eblk, 256, 0, stream>>>(dst, E, blkcnt);
    k_btotal<<<1, 256, 0, stream>>>(blkcnt, eblk, nb, E, bbase, rowptr + N);
    k_colscan<<<nb, 256, 0, stream>>>(blkcnt, eblk, bbase);
    k_bscatter<<<eblk, 256, 0, stream>>>(src, dst, E, blkcnt, pairs);
    k_bbuild<<<nb, 256, 0, stream>>>(pairs, bbase, N, rowptr, csr);

    for (int l = 0; l < NLAYERS; ++l) {
        const ushort* hin = (l == 0) ? xb : hb[l - 1];
        const float* pstats = (l == 0) ? nullptr : (stats + (l - 1) * 256);
        const float* grow_  = gamma + (l == 0 ? 0 : (l - 1)) * HID;
        const float* brow_  = beta  + (l == 0 ? 0 : (l - 1)) * HID;

        k_gin_layer<<<(N + 63) / 64, 256, 0, stream>>>(
            rowptr, csr, (const uint2*)hin, pstats, grow_, brow_,
            epsg, l, batch,
            w1h + (size_t)l * 16384, w1l + (size_t)l * 16384, b1 + l * HID,
            w2h + (size_t)l * 16384, w2l + (size_t)l * 16384, b2 + l * HID,
            hb[l], stats + l * 256, stats + l * 256 + 128, gsum, N);
    }

    k_mlp<<<NGRAPH, 128, 0, stream>>>(batch, N, gsum, stats, gamma, beta,
                                      l1w, l1b, l2w, l2b, (float*)d_out);
}

// Round 14
// 701.756 us; speedup vs baseline: 1.0328x; 1.0328x over previous
//
#include <hip/hip_runtime.h>

#define HID 128
#define NGRAPH 512
#define NLAYERS 3
#define BN_EPS 1e-5f
#define NPB 256          // nodes per bucket (CSR build)
#define EB 4096          // edges per build block

typedef __attribute__((ext_vector_type(8))) short bf16x8;
typedef __attribute__((ext_vector_type(4))) float f32x4;

__device__ inline unsigned short f2bf(float x) {
    union { float f; unsigned u; } v; v.f = x;
    unsigned r = v.u + 0x7FFFu + ((v.u >> 16) & 1u);
    return (unsigned short)(r >> 16);
}
__device__ inline float bf2f(unsigned short b) {
    union { float f; unsigned u; } v; v.u = ((unsigned)b) << 16; return v.f;
}

// ---------------------------------------------------------------------------
// prep (one launch): zero stats+gsum | W split+transpose | x -> bf16
// ---------------------------------------------------------------------------
__global__ void k_prep(float* __restrict__ stats, float* __restrict__ gsum,
                       const float4* __restrict__ x4, ushort* __restrict__ xb, int total4,
                       const float* __restrict__ W1, ushort* __restrict__ w1h, ushort* __restrict__ w1l,
                       const float* __restrict__ W2, ushort* __restrict__ w2h, ushort* __restrict__ w2l,
                       int wtotal) {
    int b = blockIdx.x, t = threadIdx.x;
    if (b < 768) {
        if (b == 0) for (int l = 0; l < NLAYERS; ++l) stats[l * 256 + t] = 0.0f;
        gsum[b * 256 + t] = 0.0f;
    } else if (b < 1152) {
        int gid = (b - 768) * 256 + t;
        const float* W; ushort *Wh, *Wl; int e;
        if (gid < wtotal) { W = W1; Wh = w1h; Wl = w1l; e = gid; }
        else              { W = W2; Wh = w2h; Wl = w2l; e = gid - wtotal; }
        if (e < wtotal) {
            int l = e >> 14, rem = e & 16383, k = rem >> 7, n = rem & 127;
            float v = W[e];
            ushort hi = f2bf(v);
            ushort lo = f2bf(v - bf2f(hi));
            int o = (l << 14) + (n << 7) + k;
            Wh[o] = hi; Wl[o] = lo;
        }
    } else {
        int i = (b - 1152) * 256 + t;
        if (i < total4) {
            float4 v = x4[i];
            uint2 p;
            p.x = ((unsigned)f2bf(v.y) << 16) | f2bf(v.x);
            p.y = ((unsigned)f2bf(v.w) << 16) | f2bf(v.z);
            ((uint2*)xb)[i] = p;
        }
    }
}

// ---------------------------------------------------------------------------
// CSR build, deterministic two-level (NO global atomics)
// ---------------------------------------------------------------------------
__global__ __launch_bounds__(256) void k_ecount(const int* __restrict__ dst, int E,
                                                int* __restrict__ blkcnt) {
    __shared__ int hist[512];
    int t = threadIdx.x;
    hist[t] = 0; hist[t + 256] = 0;
    __syncthreads();
    int base = blockIdx.x * EB;
    #pragma unroll
    for (int i = 0; i < 16; ++i) {
        int e = base + i * 256 + t;
        if (e < E) atomicAdd(&hist[dst[e] >> 8], 1);
    }
    __syncthreads();
    blkcnt[blockIdx.x * 512 + t]       = hist[t];
    blkcnt[blockIdx.x * 512 + t + 256] = hist[t + 256];
}

__global__ __launch_bounds__(256) void k_btotal(const int* __restrict__ blkcnt, int eblk,
                                                int nb, int E, int* __restrict__ bbase,
                                                int* __restrict__ rowptrN) {
    __shared__ int tot[512];
    int t = threadIdx.x;
    for (int b = t; b < 512; b += 256) {
        int s = 0;
        for (int j = 0; j < eblk; ++j) s += blkcnt[j * 512 + b];
        tot[b] = s;
    }
    __syncthreads();
    if (t == 0) {
        int run = 0;
        for (int b = 0; b < nb; ++b) { int c = tot[b]; tot[b] = run; run += c; }
        *rowptrN = E;
    }
    __syncthreads();
    for (int b = t; b < nb; b += 256) bbase[b] = tot[b];
    if (t == 0) bbase[nb] = E;
}

__global__ __launch_bounds__(256) void k_colscan(int* __restrict__ blkcnt, int eblk,
                                                 const int* __restrict__ bbase) {
    __shared__ int sh[512];
    int t = threadIdx.x;
    int b = blockIdx.x;
    for (int j = t; j < eblk; j += 256) sh[j] = blkcnt[j * 512 + b];
    __syncthreads();
    if (t == 0) {
        int run = bbase[b];
        for (int j = 0; j < eblk; ++j) { int c = sh[j]; sh[j] = run; run += c; }
    }
    __syncthreads();
    for (int j = t; j < eblk; j += 256) blkcnt[j * 512 + b] = sh[j];
}

__global__ __launch_bounds__(256) void k_bscatter(const int* __restrict__ src,
                                                  const int* __restrict__ dst, int E,
                                                  const int* __restrict__ blkcnt,
                                                  unsigned* __restrict__ pairs) {
    __shared__ int hist[512];    // local cursor (starts at 0)
    __shared__ int lbase[512];   // absolute base for this block's chunk per bucket
    int t = threadIdx.x;
    hist[t] = 0; hist[t + 256] = 0;
    lbase[t]       = blkcnt[blockIdx.x * 512 + t];
    lbase[t + 256] = blkcnt[blockIdx.x * 512 + t + 256];
    __syncthreads();
    int base = blockIdx.x * EB;
    #pragma unroll
    for (int i = 0; i < 16; ++i) {
        int e = base + i * 256 + t;
        if (e < E) {
            int d = dst[e];
            int b = d >> 8;
            int pos = lbase[b] + atomicAdd(&hist[b], 1);
            pairs[pos] = ((unsigned)(d & 255) << 24) | (unsigned)src[e];
        }
    }
}

__global__ __launch_bounds__(256) void k_bbuild(const unsigned* __restrict__ pairs,
                                                const int* __restrict__ bbase, int N,
                                                int* __restrict__ rowptr, int* __restrict__ csr) {
    __shared__ int cnt[256];
    __shared__ int off[256];
    int t = threadIdx.x;
    int b = blockIdx.x;
    int base = bbase[b], bcount = bbase[b + 1] - base;
    cnt[t] = 0;
    __syncthreads();
    for (int i = t; i < bcount; i += 256) atomicAdd(&cnt[pairs[base + i] >> 24], 1);
    __syncthreads();
    off[t] = cnt[t];
    __syncthreads();
    for (int s = 1; s < 256; s <<= 1) {
        int v = (t >= s) ? off[t - s] : 0;
        __syncthreads();
        off[t] += v;
        __syncthreads();
    }
    int excl = (t == 0) ? 0 : off[t - 1];
    int node = b * NPB + t;
    if (node < N) rowptr[node] = base + excl;
    cnt[t] = excl;                      // becomes per-node cursor
    __syncthreads();
    for (int i = t; i < bcount; i += 256) {
        unsigned p = pairs[base + i];
        int dl = p >> 24;
        int pos = base + atomicAdd(&cnt[dl], 1);
        csr[pos] = (int)(p & 0xFFFFFFu);
    }
}

// ---------------------------------------------------------------------------
// FUSED per-layer kernel: CSR gather (bf16 h) + inline BN fold of prev layer
// + MFMA MLP (A bf16, W bf16 hi+lo -> 2 MFMAs/tile) + BN stats + pool sums.
// LDS 16 KB, 8 blocks/CU.  Epilogue stores h via LDS re-stage (coalesced
// uint4, full 64B lines) — avoids write-allocate thrash of 2B stores.
// ---------------------------------------------------------------------------
__global__ __launch_bounds__(256, 8) void k_gin_layer(
        const int* __restrict__ rowptr, const int* __restrict__ csr_src,
        const uint2* __restrict__ hinb,
        const float* __restrict__ prev_stats,      // null for layer 0; else sum|sq (256)
        const float* __restrict__ g_row, const float* __restrict__ be_row,
        const float* __restrict__ eps_gin, int layer, const int* __restrict__ batch,
        const ushort* __restrict__ w1h, const ushort* __restrict__ w1l,
        const float* __restrict__ b1,
        const ushort* __restrict__ w2h, const ushort* __restrict__ w2l,
        const float* __restrict__ b2,
        ushort* __restrict__ Hout, float* __restrict__ stat_sum, float* __restrict__ stat_sq,
        float* __restrict__ gsum, int N) {
    __shared__ __align__(16) ushort smem[8192];    // 16 KB
    // phase A: z0 bf16 u4[0..1023] (64r x 16c swizzled)
    // phase Z (overlay): z1 bf16 us[0..8191]
    // phase O (overlay): z2 bf16 row-major [64][128]

    const int t = threadIdx.x;
    const int lane = t & 63;
    const int wv = t >> 6;
    const int li = lane & 15;
    const int kq = lane >> 4;
    const int n0 = wv * 32;
    const int row0 = blockIdx.x * 64;
    const int swz = (li & 7) * 4;

    // ---- gather phase: wave wv stages rows [wv*16, wv*16+16), 2 per iter ----
    {
        int half = lane >> 5;          // 0/1: which row of the pair
        int f = lane & 31;             // uint2 lane (4 bf16 features) within row
        float scv[4], shv[4];
        if (prev_stats) {
            float invn = 1.0f / (float)N;
            #pragma unroll
            for (int j = 0; j < 4; ++j) {
                int fi = f * 4 + j;
                float mu = prev_stats[fi] * invn;
                float var = prev_stats[128 + fi] * invn - mu * mu;
                float inv = rsqrtf(var + BN_EPS);
                float scj = g_row[fi] * inv;
                scv[j] = scj; shv[j] = be_row[fi] - mu * scj;
            }
        } else {
            #pragma unroll
            for (int j = 0; j < 4; ++j) { scv[j] = 1.0f; shv[j] = 0.0f; }
        }
        float e1 = 1.0f + eps_gin[layer];
        #pragma unroll
        for (int it = 0; it < 8; ++it) {
            int r = wv * 16 + it * 2 + half;      // local row
            int node = row0 + r;
            float ax = 0.f, ay = 0.f, az = 0.f, aw = 0.f;
            float cdeg = 0.f;
            if (node < N) {
                int beg = rowptr[node], end = rowptr[node + 1];
                uint2 hv = hinb[(size_t)node * 32 + f];
                ax = e1 * bf2f((ushort)hv.x); ay = e1 * bf2f((ushort)(hv.x >> 16));
                az = e1 * bf2f((ushort)hv.y); aw = e1 * bf2f((ushort)(hv.y >> 16));
                int p = beg;
                for (; p + 7 < end; p += 8) {
                    int s0 = csr_src[p],     s1 = csr_src[p + 1], s2 = csr_src[p + 2], s3 = csr_src[p + 3];
                    int s4 = csr_src[p + 4], s5 = csr_src[p + 5], s6 = csr_src[p + 6], s7 = csr_src[p + 7];
                    uint2 v0 = hinb[(size_t)s0 * 32 + f];
                    uint2 v1 = hinb[(size_t)s1 * 32 + f];
                    uint2 v2 = hinb[(size_t)s2 * 32 + f];
                    uint2 v3 = hinb[(size_t)s3 * 32 + f];
                    uint2 v4 = hinb[(size_t)s4 * 32 + f];
                    uint2 v5 = hinb[(size_t)s5 * 32 + f];
                    uint2 v6 = hinb[(size_t)s6 * 32 + f];
                    uint2 v7 = hinb[(size_t)s7 * 32 + f];
                    ax += ((bf2f((ushort)v0.x) + bf2f((ushort)v1.x)) + (bf2f((ushort)v2.x) + bf2f((ushort)v3.x)))
                        + ((bf2f((ushort)v4.x) + bf2f((ushort)v5.x)) + (bf2f((ushort)v6.x) + bf2f((ushort)v7.x)));
                    ay += ((bf2f((ushort)(v0.x >> 16)) + bf2f((ushort)(v1.x >> 16))) + (bf2f((ushort)(v2.x >> 16)) + bf2f((ushort)(v3.x >> 16))))
                        + ((bf2f((ushort)(v4.x >> 16)) + bf2f((ushort)(v5.x >> 16))) + (bf2f((ushort)(v6.x >> 16)) + bf2f((ushort)(v7.x >> 16))));
                    az += ((bf2f((ushort)v0.y) + bf2f((ushort)v1.y)) + (bf2f((ushort)v2.y) + bf2f((ushort)v3.y)))
                        + ((bf2f((ushort)v4.y) + bf2f((ushort)v5.y)) + (bf2f((ushort)v6.y) + bf2f((ushort)v7.y)));
                    aw += ((bf2f((ushort)(v0.y >> 16)) + bf2f((ushort)(v1.y >> 16))) + (bf2f((ushort)(v2.y >> 16)) + bf2f((ushort)(v3.y >> 16))))
                        + ((bf2f((ushort)(v4.y >> 16)) + bf2f((ushort)(v5.y >> 16))) + (bf2f((ushort)(v6.y >> 16)) + bf2f((ushort)(v7.y >> 16))));
                }
                for (; p < end; ++p) {
                    int s0 = csr_src[p];
                    uint2 v0 = hinb[(size_t)s0 * 32 + f];
                    ax += bf2f((ushort)v0.x); ay += bf2f((ushort)(v0.x >> 16));
                    az += bf2f((ushort)v0.y); aw += bf2f((ushort)(v0.y >> 16));
                }
                cdeg = e1 + (float)(end - beg);
            }
            float r0 = scv[0] * ax + cdeg * shv[0];
            float r1 = scv[1] * ay + cdeg * shv[1];
            float r2 = scv[2] * az + cdeg * shv[2];
            float r3 = scv[3] * aw + cdeg * shv[3];
            uint2 ph;
            ph.x = ((unsigned)f2bf(r1) << 16) | f2bf(r0);
            ph.y = ((unsigned)f2bf(r3) << 16) | f2bf(r2);
            int j = f >> 1;
            int d = r * 16 + (j ^ (r & 7));
            ((uint2*)smem)[d * 2 + (f & 1)] = ph;
        }
    }
    __syncthreads();

    f32x4 acc[4][2];
    #pragma unroll
    for (int i = 0; i < 4; ++i) {
        acc[i][0] = (f32x4){0.f, 0.f, 0.f, 0.f};
        acc[i][1] = (f32x4){0.f, 0.f, 0.f, 0.f};
    }

    // ---------------- GEMM1: z1 = z0 @ W1 (A bf16, W hi+lo from global) ----------------
    #pragma unroll
    for (int ch = 0; ch < 2; ++ch) {
        #pragma unroll
        for (int ks = 0; ks < 2; ++ks) {
            int kcol = ch * 8 + ks * 4 + kq;            // u4 col 0..15
            bf16x8 bh[2], bl[2];
            #pragma unroll
            for (int nt = 0; nt < 2; ++nt) {
                size_t wo = (size_t)(n0 + nt * 16 + li) * 128 + (ch * 64 + ks * 32 + kq * 8);
                bh[nt] = *(const bf16x8*)&w1h[wo];
                bl[nt] = *(const bf16x8*)&w1l[wo];
            }
            #pragma unroll
            for (int mt = 0; mt < 4; ++mt) {
                int r = mt * 16 + li;
                int hw = (r * 16 + (kcol ^ (li & 7))) * 8;
                bf16x8 ah = *(const bf16x8*)&smem[hw];
                #pragma unroll
                for (int nt = 0; nt < 2; ++nt) {
                    acc[mt][nt] = __builtin_amdgcn_mfma_f32_16x16x32_bf16(ah, bh[nt], acc[mt][nt], 0, 0, 0);
                    acc[mt][nt] = __builtin_amdgcn_mfma_f32_16x16x32_bf16(ah, bl[nt], acc[mt][nt], 0, 0, 0);
                }
            }
        }
    }

    // ---- z1 = relu(acc + b1) -> Z overlay (A-layout, bf16, swizzled) ----
    float bz0 = b1[n0 + li], bz1 = b1[n0 + 16 + li];
    __syncthreads();                    // all GEMM1 A-reads done before overwrite
    #pragma unroll
    for (int mt = 0; mt < 4; ++mt) {
        #pragma unroll
        for (int nt = 0; nt < 2; ++nt) {
            int c = n0 + nt * 16 + li;
            int dk = c >> 1;
            int halfbase = (dk >> 5) * 32;
            int dlow = dk & 31;
            int codd = c & 1;
            float bias = nt ? bz1 : bz0;
            #pragma unroll
            for (int reg = 0; reg < 4; ++reg) {
                int r = mt * 16 + kq * 4 + reg;
                float v = fmaxf(acc[mt][nt][reg] + bias, 0.f);
                int us = (r * 64 + halfbase + (dlow ^ ((r & 7) * 4))) * 2 + codd;
                smem[us] = f2bf(v);
            }
        }
    }
    #pragma unroll
    for (int i = 0; i < 4; ++i) {
        acc[i][0] = (f32x4){0.f, 0.f, 0.f, 0.f};
        acc[i][1] = (f32x4){0.f, 0.f, 0.f, 0.f};
    }
    __syncthreads();

    // ---------------- GEMM2: z2 = z1 @ W2 (A bf16, W hi+lo) ----------------
    #pragma unroll
    for (int ch = 0; ch < 2; ++ch) {
        #pragma unroll
        for (int ks = 0; ks < 2; ++ks) {
            bf16x8 bh[2], bl[2];
            #pragma unroll
            for (int nt = 0; nt < 2; ++nt) {
                size_t wo = (size_t)(n0 + nt * 16 + li) * 128 + (ch * 64 + ks * 32 + kq * 8);
                bh[nt] = *(const bf16x8*)&w2h[wo];
                bl[nt] = *(const bf16x8*)&w2l[wo];
            }
            int aoff = (ks * 16 + kq * 4) ^ swz;        // dwords
            #pragma unroll
            for (int mt = 0; mt < 4; ++mt) {
                int idx = ((mt * 16 + li) * 64 + ch * 32 + aoff) * 2;
                bf16x8 ah = *(const bf16x8*)&smem[idx];
                #pragma unroll
                for (int nt = 0; nt < 2; ++nt) {
                    acc[mt][nt] = __builtin_amdgcn_mfma_f32_16x16x32_bf16(ah, bh[nt], acc[mt][nt], 0, 0, 0);
                    acc[mt][nt] = __builtin_amdgcn_mfma_f32_16x16x32_bf16(ah, bl[nt], acc[mt][nt], 0, 0, 0);
                }
            }
        }
    }

    // ---- epilogue: bias+relu; z2 -> LDS (row-major); BN stats; pool sums ----
    float bb0 = b2[n0 + li], bb1 = b2[n0 + 16 + li];
    int btr[4][4];
    #pragma unroll
    for (int mt = 0; mt < 4; ++mt)
        #pragma unroll
        for (int reg = 0; reg < 4; ++reg) {
            int grow = row0 + mt * 16 + kq * 4 + reg;
            btr[mt][reg] = (grow < N) ? batch[grow] : -1;
        }
    __syncthreads();                    // all GEMM2 z1-reads done before overwrite
    float s0 = 0.f, q0 = 0.f, s1 = 0.f, q1 = 0.f;
    #pragma unroll
    for (int mt = 0; mt < 4; ++mt) {
        #pragma unroll
        for (int reg = 0; reg < 4; ++reg) {
            int r = mt * 16 + kq * 4 + reg;
            float v0 = fmaxf(acc[mt][0][reg] + bb0, 0.f);
            float v1 = fmaxf(acc[mt][1][reg] + bb1, 0.f);
            smem[r * 128 + n0 + li]      = f2bf(v0);
            smem[r * 128 + n0 + 16 + li] = f2bf(v1);
            if (btr[mt][reg] >= 0) {
                s0 += v0; q0 += v0 * v0; s1 += v1; q1 += v1 * v1;
            }
        }
    }
    __syncthreads();
    // coalesced store: 64 rows x 16 uint4 (full 64B lines)
    {
        int valid = N - row0; if (valid > 64) valid = 64;
        int tot = valid * 16;
        for (int i = t; i < tot; i += 256) {
            int r = i >> 4, c = i & 15;
            ((uint4*)&Hout[(size_t)(row0 + r) * HID])[c] = ((const uint4*)smem)[r * 16 + c];
        }
    }
    s0 += __shfl_xor(s0, 16); s0 += __shfl_xor(s0, 32);
    q0 += __shfl_xor(q0, 16); q0 += __shfl_xor(q0, 32);
    s1 += __shfl_xor(s1, 16); s1 += __shfl_xor(s1, 32);
    q1 += __shfl_xor(q1, 16); q1 += __shfl_xor(q1, 32);
    if (kq == 0) {
        unsafeAtomicAdd(&stat_sum[n0 + li], s0);
        unsafeAtomicAdd(&stat_sq[n0 + li], q0);
        unsafeAtomicAdd(&stat_sum[n0 + 16 + li], s1);
        unsafeAtomicAdd(&stat_sq[n0 + 16 + li], q1);
    }
    // per-graph raw sums (affine applied later in k_mlp)
    int lastr = N - 1; if (lastr > row0 + 63) lastr = row0 + 63;
    int g_lo = batch[row0], g_hi = batch[lastr];
    int loff = layer * HID;
    for (int g = g_lo; g <= g_hi; ++g) {
        float p0 = 0.f, p1 = 0.f;
        #pragma unroll
        for (int mt = 0; mt < 4; ++mt)
            #pragma unroll
            for (int reg = 0; reg < 4; ++reg) {
                if (btr[mt][reg] == g) {
                    p0 += fmaxf(acc[mt][0][reg] + bb0, 0.f);
                    p1 += fmaxf(acc[mt][1][reg] + bb1, 0.f);
                }
            }
        p0 += __shfl_xor(p0, 16); p0 += __shfl_xor(p0, 32);
        p1 += __shfl_xor(p1, 16); p1 += __shfl_xor(p1, 32);
        if (kq == 0) {
            unsafeAtomicAdd(&gsum[(size_t)g * 384 + loff + n0 + li], p0);
            unsafeAtomicAdd(&gsum[(size_t)g * 384 + loff + n0 + 16 + li], p1);
        }
    }
}

// ---------------------------------------------------------------------------
// final MLP: fold BN affines from raw stats, apply to per-graph sums, 2-layer head
// ---------------------------------------------------------------------------
__global__ __launch_bounds__(128) void k_mlp(const int* __restrict__ batch, int N,
                     const float* __restrict__ gsum, const float* __restrict__ stats,
                     const float* __restrict__ gamma, const float* __restrict__ beta,
                     const float* __restrict__ w1, const float* __restrict__ b1,
                     const float* __restrict__ w2, const float* __restrict__ b2,
                     float* __restrict__ out) {
    __shared__ float gl[384];
    __shared__ float hh[128];
    int g = blockIdx.x, t = threadIdx.x;   // 128 threads
    int start, end;
    { int lo = 0, hi = N; while (lo < hi) { int m = (lo + hi) >> 1; if (batch[m] < g) lo = m + 1; else hi = m; } start = lo; }
    { int lo = start, hi = N; while (lo < hi) { int m = (lo + hi) >> 1; if (batch[m] < g + 1) lo = m + 1; else hi = m; } end = lo; }
    float cnt = (float)(end - start);
    float invc = 1.0f / fmaxf(cnt, 1.0f);
    float invn = 1.0f / (float)N;
    #pragma unroll
    for (int l = 0; l < NLAYERS; ++l) {
        float mu = stats[l * 256 + t] * invn;
        float var = stats[l * 256 + 128 + t] * invn - mu * mu;
        float inv = rsqrtf(var + BN_EPS);
        float sc = gamma[l * HID + t] * inv;
        float sh = beta[l * HID + t] - mu * sc;
        gl[l * 128 + t] = (gsum[(size_t)g * 384 + l * 128 + t] * sc + sh * cnt) * invc;
    }
    __syncthreads();
    float acc = b1[t];
    for (int k = 0; k < 384; ++k) acc = fmaf(gl[k], w1[k * HID + t], acc);
    hh[t] = fmaxf(acc, 0.f);
    __syncthreads();
    if (t < 10) {
        float a2 = b2[t];
        for (int k = 0; k < 128; ++k) a2 = fmaf(hh[k], w2[k * 10 + t], a2);
        out[g * 10 + t] = a2;
    }
}

// ---------------------------------------------------------------------------
extern "C" void kernel_launch(void* const* d_in, const int* in_sizes, int n_in,
                              void* d_out, int out_size, void* d_ws, size_t ws_size,
                              hipStream_t stream) {
    const float* x     = (const float*)d_in[0];
    const int*   ei    = (const int*)d_in[1];
    const int*   batch = (const int*)d_in[2];
    const float* W1    = (const float*)d_in[3];
    const float* b1    = (const float*)d_in[4];
    const float* W2    = (const float*)d_in[5];
    const float* b2    = (const float*)d_in[6];
    const float* gamma = (const float*)d_in[7];
    const float* beta  = (const float*)d_in[8];
    const float* epsg  = (const float*)d_in[9];
    const float* l1w   = (const float*)d_in[10];
    const float* l1b   = (const float*)d_in[11];
    const float* l2w   = (const float*)d_in[12];
    const float* l2b   = (const float*)d_in[13];

    const int N = in_sizes[0] / HID;
    const int E = in_sizes[1] / 2;
    const int* src = ei;
    const int* dst = ei + E;
    const int nb = (N + NPB - 1) / NPB;           // <= 512
    const int eblk = (E + EB - 1) / EB;           // <= 512

    float* w = (float*)d_ws;
    const size_t NF = (size_t)N * HID;
    float* zbuf   = w;                                       // pairs/blkcnt scratch (CSR build only)
    ushort* xb    = (ushort*)(w + NF);                       // x as bf16 (NF ushorts)
    ushort* hb[3] = { xb + NF, xb + 2 * NF, xb + 3 * NF };   // layer outputs, bf16
    float* stats  = w + 4 * NF;       // 3 * 256 (sum|sq per layer)
    float* gsum   = stats + 768;      // 512 * 384 (per-graph raw sums)
    int*   rowptr = (int*)(gsum + (size_t)NGRAPH * 384);     // N + 1
    int*   csr    = rowptr + N + 1;                          // E
    int*   bbase  = csr + E;                                 // nb + 1
    ushort* wt  = (ushort*)(((uintptr_t)(bbase + nb + 1) + 15) & ~(uintptr_t)15);
    ushort* w1h = wt;
    ushort* w1l = wt + 49152;
    ushort* w2h = wt + 98304;
    ushort* w2l = wt + 147456;

    unsigned* pairs  = (unsigned*)zbuf;             // E uints
    int*      blkcnt = (int*)(w + 2 * 1024 * 1024); // eblk*512 (inside zbuf region)

    const int total4 = (int)(NF / 4);
    const int prep_blocks = 1152 + (total4 + 255) / 256;
    k_prep<<<prep_blocks, 256, 0, stream>>>(stats, gsum, (const float4*)x, xb, total4,
                                            W1, w1h, w1l, W2, w2h, w2l, NLAYERS * HID * HID);

    // ---- build CSR (deterministic, no global atomics) ----
    k_ecount<<<eblk, 256, 0, stream>>>(dst, E, blkcnt);
    k_btotal<<<1, 256, 0, stream>>>(blkcnt, eblk, nb, E, bbase, rowptr + N);
    k_colscan<<<nb, 256, 0, stream>>>(blkcnt, eblk, bbase);
    k_bscatter<<<eblk, 256, 0, stream>>>(src, dst, E, blkcnt, pairs);
    k_bbuild<<<nb, 256, 0, stream>>>(pairs, bbase, N, rowptr, csr);

    for (int l = 0; l < NLAYERS; ++l) {
        const ushort* hin = (l == 0) ? xb : hb[l - 1];
        const float* pstats = (l == 0) ? nullptr : (stats + (l - 1) * 256);
        const float* grow_  = gamma + (l == 0 ? 0 : (l - 1)) * HID;
        const float* brow_  = beta  + (l == 0 ? 0 : (l - 1)) * HID;

        k_gin_layer<<<(N + 63) / 64, 256, 0, stream>>>(
            rowptr, csr, (const uint2*)hin, pstats, grow_, brow_,
            epsg, l, batch,
            w1h + (size_t)l * 16384, w1l + (size_t)l * 16384, b1 + l * HID,
            w2h + (size_t)l * 16384, w2l + (size_t)l * 16384, b2 + l * HID,
            hb[l], stats + l * 256, stats + l * 256 + 128, gsum, N);
    }

    k_mlp<<<NGRAPH, 128, 0, stream>>>(batch, N, gsum, stats, gamma, beta,
                                      l1w, l1b, l2w, l2b, (float*)d_out);
}